// Round 1
// baseline (523.240 us; speedup 1.0000x reference)
//
#include <hip/hip_runtime.h>
#include <hip/hip_bf16.h>
#include <math.h>

#define T_LEN 2048
#define D_DIM 256
#define H_NUM 8
#define DH_DIM 32
#define B_NUM 4
#define M_ROWS (B_NUM * T_LEN)   // 8192
#define LN_EPS 1e-5f

// ---------------------------------------------------------------------------
// Generic 64x64-tile GEMM: C[M,N] = A[M,K] @ W[N,K]^T + bias (optional relu)
// blockIdx.x -> 64-row tile, blockIdx.y -> 64-col tile. 256 threads, 4x4 reg tile.
// ---------------------------------------------------------------------------
template<int K, bool RELU>
__global__ __launch_bounds__(256) void gemm_tile64(
    const float* __restrict__ A, const float* __restrict__ W,
    const float* __restrict__ bias, float* __restrict__ C, int N)
{
    constexpr int F4R = K / 4;       // float4 per A row
    constexpr int STR = F4R + 1;     // padded row stride (float4) -> 2-way-free banks
    __shared__ float4 As4[64 * STR];

    const int m0 = blockIdx.x * 64;
    const int n0 = blockIdx.y * 64;

    const float4* src = reinterpret_cast<const float4*>(A + (size_t)m0 * K);
    for (int i = threadIdx.x; i < 64 * F4R; i += 256) {
        int r = i / F4R;
        int c = i - r * F4R;
        As4[r * STR + c] = src[i];
    }
    __syncthreads();

    const int ty = threadIdx.x >> 4;   // 0..15 -> rows ty*4..+3
    const int tx = threadIdx.x & 15;   // 0..15 -> cols n0+tx*4..+3

    float acc[4][4] = {};
    const float* w0 = W + (size_t)(n0 + tx * 4) * K;

    for (int k4 = 0; k4 < F4R; ++k4) {
        float4 a[4], w[4];
        #pragma unroll
        for (int r = 0; r < 4; ++r) a[r] = As4[(ty * 4 + r) * STR + k4];
        #pragma unroll
        for (int c = 0; c < 4; ++c)
            w[c] = *reinterpret_cast<const float4*>(w0 + (size_t)c * K + k4 * 4);
        #pragma unroll
        for (int r = 0; r < 4; ++r)
            #pragma unroll
            for (int c = 0; c < 4; ++c)
                acc[r][c] += a[r].x * w[c].x + a[r].y * w[c].y
                           + a[r].z * w[c].z + a[r].w * w[c].w;
    }

    float4 bv = *reinterpret_cast<const float4*>(bias + n0 + tx * 4);
    #pragma unroll
    for (int r = 0; r < 4; ++r) {
        float4 o;
        o.x = acc[r][0] + bv.x;
        o.y = acc[r][1] + bv.y;
        o.z = acc[r][2] + bv.z;
        o.w = acc[r][3] + bv.w;
        if (RELU) {
            o.x = fmaxf(o.x, 0.f); o.y = fmaxf(o.y, 0.f);
            o.z = fmaxf(o.z, 0.f); o.w = fmaxf(o.w, 0.f);
        }
        *reinterpret_cast<float4*>(C + (size_t)(m0 + ty * 4 + r) * N + n0 + tx * 4) = o;
    }
}

// ---------------------------------------------------------------------------
// Windowed local attention. Window = [t-4, t+4] clipped to [0, T-1].
// One block = (b, h, 256 queries). K/V window staged in LDS (stride 33 floats).
// qkv layout: [B, T, 768] with q cols [0,256), k [256,512), v [512,768).
// Output o: [B, T, 256] head-major cols (h*32 + d).
// ---------------------------------------------------------------------------
__global__ __launch_bounds__(256) void attn_local(
    const float* __restrict__ qkv, float* __restrict__ o)
{
    constexpr int TS = 256;
    constexpr int WL = TS + 8;   // 264 staged key rows
    constexpr int STR = 33;      // padded float stride
    __shared__ float kt[WL * STR];
    __shared__ float vt[WL * STR];

    const int t0 = blockIdx.x * TS;
    const int h  = blockIdx.y;
    const int b  = blockIdx.z;
    const float* base = qkv + (size_t)b * T_LEN * 768;

    for (int i = threadIdx.x; i < WL * 8; i += 256) {
        int row = i >> 3;
        int c4  = (i & 7) * 4;
        int key = min(max(t0 - 4 + row, 0), T_LEN - 1);
        float4 kv = *reinterpret_cast<const float4*>(base + (size_t)key * 768 + 256 + h * DH_DIM + c4);
        float4 vv = *reinterpret_cast<const float4*>(base + (size_t)key * 768 + 512 + h * DH_DIM + c4);
        float* kd = &kt[row * STR + c4];
        float* vd = &vt[row * STR + c4];
        kd[0] = kv.x; kd[1] = kv.y; kd[2] = kv.z; kd[3] = kv.w;
        vd[0] = vv.x; vd[1] = vv.y; vd[2] = vv.z; vd[3] = vv.w;
    }
    __syncthreads();

    const int t = t0 + threadIdx.x;
    float q[DH_DIM];
    {
        const float* qp = base + (size_t)t * 768 + h * DH_DIM;
        #pragma unroll
        for (int j = 0; j < 8; ++j) {
            float4 v = *reinterpret_cast<const float4*>(qp + j * 4);
            q[j * 4 + 0] = v.x; q[j * 4 + 1] = v.y; q[j * 4 + 2] = v.z; q[j * 4 + 3] = v.w;
        }
    }

    const int s = max(0, t - 4);
    const int e = min(T_LEN - 1, t + 4);
    const int nw = e - s + 1;

    float sc[9];
    float mx = -1e30f;
    for (int j = 0; j < nw; ++j) {
        const float* kr = &kt[(s + j - t0 + 4) * STR];
        float d = 0.f;
        #pragma unroll
        for (int c = 0; c < DH_DIM; ++c) d += q[c] * kr[c];
        d *= 0.17677669529663687f;  // 1/sqrt(32)
        sc[j] = d;
        mx = fmaxf(mx, d);
    }
    float sum = 0.f;
    for (int j = 0; j < nw; ++j) { sc[j] = expf(sc[j] - mx); sum += sc[j]; }
    const float inv = 1.f / sum;

    float ov[DH_DIM] = {};
    for (int j = 0; j < nw; ++j) {
        const float p = sc[j] * inv;
        const float* vr = &vt[(s + j - t0 + 4) * STR];
        #pragma unroll
        for (int c = 0; c < DH_DIM; ++c) ov[c] += p * vr[c];
    }

    float* op = o + ((size_t)b * T_LEN + t) * D_DIM + h * DH_DIM;
    #pragma unroll
    for (int j = 0; j < 8; ++j) {
        float4 v;
        v.x = ov[j * 4 + 0]; v.y = ov[j * 4 + 1]; v.z = ov[j * 4 + 2]; v.w = ov[j * 4 + 3];
        *reinterpret_cast<float4*>(op + j * 4) = v;
    }
}

// ---------------------------------------------------------------------------
// out = LayerNorm(res + A @ W^T + bias) * gamma + beta.  N fixed = 256.
// Block = 16 rows x 256 cols, 256 threads, 4x4 reg tile, fused LN.
// ---------------------------------------------------------------------------
template<int K>
__global__ __launch_bounds__(256) void proj_res_ln(
    const float* __restrict__ A, const float* __restrict__ W,
    const float* __restrict__ bias, const float* __restrict__ res,
    const float* __restrict__ gamma, const float* __restrict__ beta,
    float* __restrict__ out)
{
    constexpr int F4R = K / 4;
    constexpr int STR = F4R + 1;
    __shared__ float4 As4[16 * STR];
    __shared__ float  Xs[16][D_DIM + 4];

    const int m0 = blockIdx.x * 16;

    const float4* src = reinterpret_cast<const float4*>(A + (size_t)m0 * K);
    for (int i = threadIdx.x; i < 16 * F4R; i += 256) {
        int r = i / F4R;
        int c = i - r * F4R;
        As4[r * STR + c] = src[i];
    }
    __syncthreads();

    const int ty = threadIdx.x >> 6;   // 0..3 -> rows ty*4..+3
    const int tx = threadIdx.x & 63;   // 0..63 -> cols tx*4..+3

    float acc[4][4] = {};
    const float* w0 = W + (size_t)(tx * 4) * K;

    for (int k4 = 0; k4 < F4R; ++k4) {
        float4 a[4], w[4];
        #pragma unroll
        for (int r = 0; r < 4; ++r) a[r] = As4[(ty * 4 + r) * STR + k4];
        #pragma unroll
        for (int c = 0; c < 4; ++c)
            w[c] = *reinterpret_cast<const float4*>(w0 + (size_t)c * K + k4 * 4);
        #pragma unroll
        for (int r = 0; r < 4; ++r)
            #pragma unroll
            for (int c = 0; c < 4; ++c)
                acc[r][c] += a[r].x * w[c].x + a[r].y * w[c].y
                           + a[r].z * w[c].z + a[r].w * w[c].w;
    }

    float4 bv = *reinterpret_cast<const float4*>(bias + tx * 4);
    #pragma unroll
    for (int r = 0; r < 4; ++r) {
        const int row = m0 + ty * 4 + r;
        float4 rv = *reinterpret_cast<const float4*>(res + (size_t)row * D_DIM + tx * 4);
        float* xd = &Xs[ty * 4 + r][tx * 4];
        xd[0] = acc[r][0] + bv.x + rv.x;
        xd[1] = acc[r][1] + bv.y + rv.y;
        xd[2] = acc[r][2] + bv.z + rv.z;
        xd[3] = acc[r][3] + bv.w + rv.w;
    }
    __syncthreads();

    // LayerNorm: 16 lanes per row
    const int g = threadIdx.x >> 4;   // row 0..15
    const int l = threadIdx.x & 15;
    float s = 0.f, sq = 0.f;
    #pragma unroll
    for (int j = 0; j < 4; ++j) {
        float4 v = *reinterpret_cast<const float4*>(&Xs[g][l * 16 + j * 4]);
        s  += v.x + v.y + v.z + v.w;
        sq += v.x * v.x + v.y * v.y + v.z * v.z + v.w * v.w;
    }
    #pragma unroll
    for (int m = 1; m <= 8; m <<= 1) {
        s  += __shfl_xor(s, m);
        sq += __shfl_xor(sq, m);
    }
    const float mean = s * (1.f / D_DIM);
    const float var  = sq * (1.f / D_DIM) - mean * mean;
    const float rstd = rsqrtf(var + LN_EPS);

    const int row = m0 + g;
    #pragma unroll
    for (int j = 0; j < 4; ++j) {
        const int c = l * 16 + j * 4;
        float4 v  = *reinterpret_cast<const float4*>(&Xs[g][c]);
        float4 gm = *reinterpret_cast<const float4*>(gamma + c);
        float4 bt = *reinterpret_cast<const float4*>(beta + c);
        float4 o;
        o.x = (v.x - mean) * rstd * gm.x + bt.x;
        o.y = (v.y - mean) * rstd * gm.y + bt.y;
        o.z = (v.z - mean) * rstd * gm.z + bt.z;
        o.w = (v.w - mean) * rstd * gm.w + bt.w;
        *reinterpret_cast<float4*>(out + (size_t)row * D_DIM + c) = o;
    }
}

// ---------------------------------------------------------------------------
extern "C" void kernel_launch(void* const* d_in, const int* in_sizes, int n_in,
                              void* d_out, int out_size, void* d_ws, size_t ws_size,
                              hipStream_t stream) {
    const float* features = (const float*)d_in[0];
    const float* w_qkv    = (const float*)d_in[1];
    const float* b_qkv    = (const float*)d_in[2];
    const float* w_out    = (const float*)d_in[3];
    const float* b_out    = (const float*)d_in[4];
    const float* w1       = (const float*)d_in[5];
    const float* b1       = (const float*)d_in[6];
    const float* w2       = (const float*)d_in[7];
    const float* b2       = (const float*)d_in[8];
    const float* g1       = (const float*)d_in[9];
    const float* be1      = (const float*)d_in[10];
    const float* g2       = (const float*)d_in[11];
    const float* be2      = (const float*)d_in[12];
    // d_in[13] (mask) is structurally determined by WIN=9 -> not read.

    float* ws   = (float*)d_ws;
    float* qkv  = ws;                                   // [8192][768]
    float* o    = qkv + (size_t)M_ROWS * 768;           // [8192][256]
    float* x    = o   + (size_t)M_ROWS * D_DIM;         // [8192][256]
    float* hff  = qkv;                                  // alias: qkv dead after attn

    // 1) QKV projection
    gemm_tile64<256, false><<<dim3(M_ROWS / 64, 12), 256, 0, stream>>>(
        features, w_qkv, b_qkv, qkv, 768);
    // 2) windowed attention
    attn_local<<<dim3(T_LEN / 256, H_NUM, B_NUM), 256, 0, stream>>>(qkv, o);
    // 3) out-proj + residual + LN1
    proj_res_ln<256><<<M_ROWS / 16, 256, 0, stream>>>(
        o, w_out, b_out, features, g1, be1, x);
    // 4) FFN up + relu
    gemm_tile64<256, true><<<dim3(M_ROWS / 64, 8), 256, 0, stream>>>(
        x, w1, b1, hff, 512);
    // 5) FFN down + residual + LN2 -> out
    proj_res_ln<512><<<M_ROWS / 16, 256, 0, stream>>>(
        hff, w2, b2, x, g2, be2, (float*)d_out);
}

// Round 2
// 80.679 us; speedup vs baseline: 6.4854x; 6.4854x over previous
//
#include <hip/hip_runtime.h>
#include <math.h>

#define T_LEN 2048
#define D_DIM 256
#define H_NUM 8
#define DH_DIM 32
#define B_NUM 4
#define M_ROWS (B_NUM * T_LEN)   // 8192
#define LN_EPS 1e-5f

using bf16x8 = __attribute__((ext_vector_type(8))) short;
using f32x4  = __attribute__((ext_vector_type(4))) float;

// fp32 -> bf16 round-to-nearest-even (bit trick; inputs are finite)
__device__ __forceinline__ unsigned short f2bf(float f) {
    unsigned int u = __float_as_uint(f);
    u += 0x7FFFu + ((u >> 16) & 1u);
    return (unsigned short)(u >> 16);
}

// ---------------------------------------------------------------------------
// C[M,N] = A[M,K] @ W[N,K]^T + bias (+res) (+relu), bf16 MFMA, fp32 I/O.
// 128x128 tile, BK=64, 256 threads = 4 waves (2x2), 64x64 per wave.
// LDS [128][64] bf16, XOR-swizzled byte ^= (row&7)<<4 on write AND read (T2).
// ---------------------------------------------------------------------------
template<int K, bool RELU, bool HAS_RES>
__global__ __launch_bounds__(256) void mfma_gemm128(
    const float* __restrict__ A, const float* __restrict__ W,
    const float* __restrict__ bias, const float* __restrict__ res,
    float* __restrict__ C, int N)
{
    __shared__ int4 AsB[1024];   // 16 KB = 128 rows x 64 bf16
    __shared__ int4 BsB[1024];
    char* As = (char*)AsB;
    char* Bs = (char*)BsB;

    const int tid  = threadIdx.x;
    const int lane = tid & 63;
    const int wid  = tid >> 6;
    const int wr = wid >> 1, wc = wid & 1;
    const int m0 = blockIdx.x * 128;
    const int n0 = blockIdx.y * 128;

    f32x4 acc[4][4];
    #pragma unroll
    for (int m = 0; m < 4; ++m)
        #pragma unroll
        for (int n = 0; n < 4; ++n) acc[m][n] = (f32x4)(0.f);

    for (int k0 = 0; k0 < K; k0 += 64) {
        // ---- stage A tile: 1024 chunks of 8 bf16, 4 per thread ----
        #pragma unroll
        for (int i0 = 0; i0 < 1024; i0 += 256) {
            const int i   = i0 + tid;
            const int row = i >> 3, k8 = i & 7;
            const float* ga = A + (size_t)(m0 + row) * K + (k0 + k8 * 8);
            float4 a0 = *(const float4*)ga;
            float4 a1 = *(const float4*)(ga + 4);
            union { unsigned short us[8]; int4 v; } pk;
            pk.us[0] = f2bf(a0.x); pk.us[1] = f2bf(a0.y);
            pk.us[2] = f2bf(a0.z); pk.us[3] = f2bf(a0.w);
            pk.us[4] = f2bf(a1.x); pk.us[5] = f2bf(a1.y);
            pk.us[6] = f2bf(a1.z); pk.us[7] = f2bf(a1.w);
            *(int4*)(As + ((row * 128 + k8 * 16) ^ ((row & 7) << 4))) = pk.v;
        }
        // ---- stage B tile (W rows n0..n0+127) ----
        #pragma unroll
        for (int i0 = 0; i0 < 1024; i0 += 256) {
            const int i   = i0 + tid;
            const int row = i >> 3, k8 = i & 7;
            const float* gb = W + (size_t)(n0 + row) * K + (k0 + k8 * 8);
            float4 b0 = *(const float4*)gb;
            float4 b1 = *(const float4*)(gb + 4);
            union { unsigned short us[8]; int4 v; } pk;
            pk.us[0] = f2bf(b0.x); pk.us[1] = f2bf(b0.y);
            pk.us[2] = f2bf(b0.z); pk.us[3] = f2bf(b0.w);
            pk.us[4] = f2bf(b1.x); pk.us[5] = f2bf(b1.y);
            pk.us[6] = f2bf(b1.z); pk.us[7] = f2bf(b1.w);
            *(int4*)(Bs + ((row * 128 + k8 * 16) ^ ((row & 7) << 4))) = pk.v;
        }
        __syncthreads();

        #pragma unroll
        for (int ks = 0; ks < 2; ++ks) {
            bf16x8 af[4], bfr[4];
            #pragma unroll
            for (int m = 0; m < 4; ++m) {
                const int rl  = wr * 64 + m * 16 + (lane & 15);
                const int off = (rl * 128 + ks * 64 + (lane >> 4) * 16) ^ ((rl & 7) << 4);
                af[m] = *(const bf16x8*)(As + off);
            }
            #pragma unroll
            for (int n = 0; n < 4; ++n) {
                const int rl  = wc * 64 + n * 16 + (lane & 15);
                const int off = (rl * 128 + ks * 64 + (lane >> 4) * 16) ^ ((rl & 7) << 4);
                bfr[n] = *(const bf16x8*)(Bs + off);
            }
            #pragma unroll
            for (int m = 0; m < 4; ++m)
                #pragma unroll
                for (int n = 0; n < 4; ++n)
                    acc[m][n] = __builtin_amdgcn_mfma_f32_16x16x32_bf16(
                        af[m], bfr[n], acc[m][n], 0, 0, 0);
        }
        __syncthreads();
    }

    // ---- epilogue: bias (+res) (+relu), fp32 store ----
    #pragma unroll
    for (int n = 0; n < 4; ++n) {
        const int c  = n0 + wc * 64 + n * 16 + (lane & 15);
        const float bv = bias[c];
        #pragma unroll
        for (int m = 0; m < 4; ++m) {
            const int rbase = m0 + wr * 64 + m * 16 + ((lane >> 4) << 2);
            #pragma unroll
            for (int j = 0; j < 4; ++j) {
                float v = acc[m][n][j] + bv;
                const int r = rbase + j;
                if (HAS_RES) v += res[(size_t)r * N + c];
                if (RELU)    v = fmaxf(v, 0.f);
                C[(size_t)r * N + c] = v;
            }
        }
    }
}

// ---------------------------------------------------------------------------
// Windowed local attention (unchanged from round 1, fp32).
// ---------------------------------------------------------------------------
__global__ __launch_bounds__(256) void attn_local(
    const float* __restrict__ qkv, float* __restrict__ o)
{
    constexpr int TS = 256;
    constexpr int WL = TS + 8;
    constexpr int STR = 33;
    __shared__ float kt[WL * STR];
    __shared__ float vt[WL * STR];

    const int t0 = blockIdx.x * TS;
    const int h  = blockIdx.y;
    const int b  = blockIdx.z;
    const float* base = qkv + (size_t)b * T_LEN * 768;

    for (int i = threadIdx.x; i < WL * 8; i += 256) {
        int row = i >> 3;
        int c4  = (i & 7) * 4;
        int key = min(max(t0 - 4 + row, 0), T_LEN - 1);
        float4 kv = *reinterpret_cast<const float4*>(base + (size_t)key * 768 + 256 + h * DH_DIM + c4);
        float4 vv = *reinterpret_cast<const float4*>(base + (size_t)key * 768 + 512 + h * DH_DIM + c4);
        float* kd = &kt[row * STR + c4];
        float* vd = &vt[row * STR + c4];
        kd[0] = kv.x; kd[1] = kv.y; kd[2] = kv.z; kd[3] = kv.w;
        vd[0] = vv.x; vd[1] = vv.y; vd[2] = vv.z; vd[3] = vv.w;
    }
    __syncthreads();

    const int t = t0 + threadIdx.x;
    float q[DH_DIM];
    {
        const float* qp = base + (size_t)t * 768 + h * DH_DIM;
        #pragma unroll
        for (int j = 0; j < 8; ++j) {
            float4 v = *reinterpret_cast<const float4*>(qp + j * 4);
            q[j * 4 + 0] = v.x; q[j * 4 + 1] = v.y;
            q[j * 4 + 2] = v.z; q[j * 4 + 3] = v.w;
        }
    }

    const int s = max(0, t - 4);
    const int e = min(T_LEN - 1, t + 4);
    const int nw = e - s + 1;

    float sc[9];
    float mx = -1e30f;
    for (int j = 0; j < nw; ++j) {
        const float* kr = &kt[(s + j - t0 + 4) * STR];
        float d = 0.f;
        #pragma unroll
        for (int c = 0; c < DH_DIM; ++c) d += q[c] * kr[c];
        d *= 0.17677669529663687f;
        sc[j] = d;
        mx = fmaxf(mx, d);
    }
    float sum = 0.f;
    for (int j = 0; j < nw; ++j) { sc[j] = expf(sc[j] - mx); sum += sc[j]; }
    const float inv = 1.f / sum;

    float ov[DH_DIM] = {};
    for (int j = 0; j < nw; ++j) {
        const float p = sc[j] * inv;
        const float* vr = &vt[(s + j - t0 + 4) * STR];
        #pragma unroll
        for (int c = 0; c < DH_DIM; ++c) ov[c] += p * vr[c];
    }

    float* op = o + ((size_t)b * T_LEN + t) * D_DIM + h * DH_DIM;
    #pragma unroll
    for (int j = 0; j < 8; ++j) {
        float4 v;
        v.x = ov[j * 4 + 0]; v.y = ov[j * 4 + 1];
        v.z = ov[j * 4 + 2]; v.w = ov[j * 4 + 3];
        *reinterpret_cast<float4*>(op + j * 4) = v;
    }
}

// ---------------------------------------------------------------------------
// LayerNorm over rows of 256. One wave per row, 4 rows per block.
// ---------------------------------------------------------------------------
__global__ __launch_bounds__(256) void ln_rows(
    const float* __restrict__ X, const float* __restrict__ gamma,
    const float* __restrict__ beta, float* __restrict__ out)
{
    const int row  = blockIdx.x * 4 + (threadIdx.x >> 6);
    const int lane = threadIdx.x & 63;
    const float* xr = X + (size_t)row * D_DIM;

    float4 v = *(const float4*)(xr + lane * 4);
    float s  = v.x + v.y + v.z + v.w;
    float sq = v.x * v.x + v.y * v.y + v.z * v.z + v.w * v.w;
    #pragma unroll
    for (int m = 1; m <= 32; m <<= 1) {
        s  += __shfl_xor(s, m);
        sq += __shfl_xor(sq, m);
    }
    const float mean = s * (1.f / D_DIM);
    const float var  = sq * (1.f / D_DIM) - mean * mean;
    const float rstd = rsqrtf(var + LN_EPS);

    float4 gm = *(const float4*)(gamma + lane * 4);
    float4 bt = *(const float4*)(beta + lane * 4);
    float4 o;
    o.x = (v.x - mean) * rstd * gm.x + bt.x;
    o.y = (v.y - mean) * rstd * gm.y + bt.y;
    o.z = (v.z - mean) * rstd * gm.z + bt.z;
    o.w = (v.w - mean) * rstd * gm.w + bt.w;
    *(float4*)(out + (size_t)row * D_DIM + lane * 4) = o;
}

// ---------------------------------------------------------------------------
extern "C" void kernel_launch(void* const* d_in, const int* in_sizes, int n_in,
                              void* d_out, int out_size, void* d_ws, size_t ws_size,
                              hipStream_t stream) {
    const float* features = (const float*)d_in[0];
    const float* w_qkv    = (const float*)d_in[1];
    const float* b_qkv    = (const float*)d_in[2];
    const float* w_out    = (const float*)d_in[3];
    const float* b_out    = (const float*)d_in[4];
    const float* w1       = (const float*)d_in[5];
    const float* b1       = (const float*)d_in[6];
    const float* w2       = (const float*)d_in[7];
    const float* b2       = (const float*)d_in[8];
    const float* g1       = (const float*)d_in[9];
    const float* be1      = (const float*)d_in[10];
    const float* g2       = (const float*)d_in[11];
    const float* be2      = (const float*)d_in[12];
    // d_in[13] (mask) is structurally determined by WIN=9 -> not read.

    float* ws = (float*)d_ws;
    // layout (floats), high-water 10,485,760 = round-1 footprint:
    float* qkv   = ws;                    // [8192][768]  = 6,291,456 (dead after attn)
    float* x     = ws;                    // [8192][256]  reuses qkv[0:2.1M]   (after LN1)
    float* hid   = ws + 2097152;          // [8192][512]  reuses qkv[2.1M:6.3M]
    float* o     = ws + 6291456;          // [8192][256]
    float* y_pre = ws + 6291456;          // reuses o (o dead after out-proj GEMM)
    float* x_pre = ws + 8388608;          // [8192][256]

    // 1) QKV projection: [8192,768]
    mfma_gemm128<256, false, false><<<dim3(64, 6), 256, 0, stream>>>(
        features, w_qkv, b_qkv, nullptr, qkv, 768);
    // 2) windowed attention -> o
    attn_local<<<dim3(T_LEN / 256, H_NUM, B_NUM), 256, 0, stream>>>(qkv, o);
    // 3) out-proj + bias + residual(features) -> x_pre
    mfma_gemm128<256, false, true><<<dim3(64, 2), 256, 0, stream>>>(
        o, w_out, b_out, features, x_pre, 256);
    // 4) LN1 -> x
    ln_rows<<<M_ROWS / 4, 256, 0, stream>>>(x_pre, g1, be1, x);
    // 5) FFN up + relu -> hid
    mfma_gemm128<256, true, false><<<dim3(64, 4), 256, 0, stream>>>(
        x, w1, b1, nullptr, hid, 512);
    // 6) FFN down + bias + residual(x) -> y_pre
    mfma_gemm128<512, false, true><<<dim3(64, 2), 256, 0, stream>>>(
        hid, w2, b2, x, y_pre, 256);
    // 7) LN2 -> out
    ln_rows<<<M_ROWS / 4, 256, 0, stream>>>(y_pre, g2, be2, (float*)d_out);
}

// Round 3
// 65.458 us; speedup vs baseline: 7.9935x; 1.2325x over previous
//
#include <hip/hip_runtime.h>
#include <math.h>

#define T_LEN 2048
#define D_DIM 256
#define H_NUM 8
#define B_NUM 4
#define M_ROWS 8192
#define LN_EPS 1e-5f

using u16x8  = __attribute__((ext_vector_type(8))) unsigned short;
using u16x4  = __attribute__((ext_vector_type(4))) unsigned short;
using bf16x8 = __attribute__((ext_vector_type(8))) short;
using f32x4  = __attribute__((ext_vector_type(4))) float;

// fp32 -> bf16 RNE (finite inputs)
__device__ __forceinline__ unsigned short f2bf(float f) {
    unsigned int u = __float_as_uint(f);
    u += 0x7FFFu + ((u >> 16) & 1u);
    return (unsigned short)(u >> 16);
}
__device__ __forceinline__ float bf2f(unsigned short u) {
    return __uint_as_float(((unsigned int)u) << 16);
}
// 16-byte async global->LDS (dest must be wave-uniform base + lane*16)
__device__ __forceinline__ void gload16(const void* g, void* l) {
    __builtin_amdgcn_global_load_lds(
        (const __attribute__((address_space(1))) unsigned int*)g,
        (__attribute__((address_space(3))) unsigned int*)l, 16, 0, 0);
}

// ---------------------------------------------------------------------------
// One-shot fp32 -> bf16 of {features, w_qkv, w_out, w1, w2} into ws bf16 zone.
// Segment offsets (elements): 0, 2097152, 2293760, 2359296, 2490368, 2621440.
// ---------------------------------------------------------------------------
__global__ __launch_bounds__(256) void to_bf16_multi(
    const float* __restrict__ s0, const float* __restrict__ s1,
    const float* __restrict__ s2, const float* __restrict__ s3,
    const float* __restrict__ s4, unsigned short* __restrict__ dst)
{
    const long i8 = ((long)blockIdx.x * 256 + threadIdx.x) * 8;
    const float* src; long off;
    if (i8 < 2097152)      { src = s0; off = 0; }
    else if (i8 < 2293760) { src = s1; off = 2097152; }
    else if (i8 < 2359296) { src = s2; off = 2293760; }
    else if (i8 < 2490368) { src = s3; off = 2359296; }
    else                   { src = s4; off = 2490368; }
    const float4 a = *(const float4*)(src + (i8 - off));
    const float4 b = *(const float4*)(src + (i8 - off) + 4);
    u16x8 p;
    p[0] = f2bf(a.x); p[1] = f2bf(a.y); p[2] = f2bf(a.z); p[3] = f2bf(a.w);
    p[4] = f2bf(b.x); p[5] = f2bf(b.y); p[6] = f2bf(b.z); p[7] = f2bf(b.w);
    *(u16x8*)(dst + i8) = p;
}

// ---------------------------------------------------------------------------
// C[M,N](bf16) = A[M,K](bf16) @ W[N,K](bf16)^T + bias(f32), optional relu.
// 128x128 tile, BK=64, 4 waves (2x2), m97 structure: linear LDS + gload_lds.
// ---------------------------------------------------------------------------
template<int K, bool RELU>
__global__ __launch_bounds__(256) void gemm_bf16_128(
    const unsigned short* __restrict__ A, const unsigned short* __restrict__ W,
    const float* __restrict__ bias, unsigned short* __restrict__ C, int N)
{
    __shared__ int4 smem4[2048];                 // 32 KB
    char* As = (char*)smem4;                     // [128][64] bf16
    char* Bs = (char*)smem4 + 16384;

    const int tid = threadIdx.x;
    const int lane = tid & 63, wid = tid >> 6;
    const int wr = wid >> 1, wc = wid & 1;
    const int m0 = blockIdx.x * 128, n0 = blockIdx.y * 128;

    f32x4 acc[4][4];
    #pragma unroll
    for (int m = 0; m < 4; ++m)
        #pragma unroll
        for (int n = 0; n < 4; ++n) acc[m][n] = (f32x4)(0.f);

    for (int k0 = 0; k0 < K; k0 += 64) {
        #pragma unroll
        for (int j = 0; j < 4; ++j) {
            const int i = j * 256 + tid;
            const int row = i >> 3, k8 = i & 7;
            gload16(A + (size_t)(m0 + row) * K + k0 + k8 * 8, As + i * 16);
            gload16(W + (size_t)(n0 + row) * K + k0 + k8 * 8, Bs + i * 16);
        }
        __syncthreads();
        #pragma unroll
        for (int ks = 0; ks < 2; ++ks) {
            bf16x8 af[4], bfr[4];
            #pragma unroll
            for (int m = 0; m < 4; ++m) {
                const int off = (wr * 64 + m * 16 + (lane & 15)) * 128
                              + ks * 64 + (lane >> 4) * 16;
                af[m] = *(const bf16x8*)(As + off);
            }
            #pragma unroll
            for (int n = 0; n < 4; ++n) {
                const int off = (wc * 64 + n * 16 + (lane & 15)) * 128
                              + ks * 64 + (lane >> 4) * 16;
                bfr[n] = *(const bf16x8*)(Bs + off);
            }
            #pragma unroll
            for (int m = 0; m < 4; ++m)
                #pragma unroll
                for (int n = 0; n < 4; ++n)
                    acc[m][n] = __builtin_amdgcn_mfma_f32_16x16x32_bf16(
                        af[m], bfr[n], acc[m][n], 0, 0, 0);
        }
        __syncthreads();
    }

    #pragma unroll
    for (int n = 0; n < 4; ++n) {
        const int c = n0 + wc * 64 + n * 16 + (lane & 15);
        const float bv = bias[c];
        #pragma unroll
        for (int m = 0; m < 4; ++m) {
            const int rbase = m0 + wr * 64 + m * 16 + ((lane >> 4) << 2);
            #pragma unroll
            for (int j = 0; j < 4; ++j) {
                float v = acc[m][n][j] + bv;
                if (RELU) v = fmaxf(v, 0.f);
                C[(size_t)(rbase + j) * N + c] = f2bf(v);
            }
        }
    }
}

// ---------------------------------------------------------------------------
// out(rows M, 256) = LayerNorm(A@W^T + bias + res) * gamma + beta.
// 32x256 tile (full row in block), 4 waves (1x4), fused LN epilogue.
// ---------------------------------------------------------------------------
template<int K, bool RES_F32, bool OUT_F32>
__global__ __launch_bounds__(256) void gemm_ln32(
    const unsigned short* __restrict__ A, const unsigned short* __restrict__ W,
    const float* __restrict__ bias, const void* __restrict__ resv,
    const float* __restrict__ gamma, const float* __restrict__ beta,
    void* __restrict__ outv)
{
    __shared__ int4 smem4[2304];                 // 36864 B
    char* As = (char*)smem4;                     // [32][64] bf16  = 4096 B
    char* Bs = (char*)smem4 + 4096;              // [256][64] bf16 = 32768 B
    float* Xs = (float*)smem4;                   // [32][264] f32 (union, post-loop)

    const int tid = threadIdx.x;
    const int lane = tid & 63, wid = tid >> 6;
    const int m0 = blockIdx.x * 32;

    f32x4 acc[2][4];
    #pragma unroll
    for (int m = 0; m < 2; ++m)
        #pragma unroll
        for (int n = 0; n < 4; ++n) acc[m][n] = (f32x4)(0.f);

    for (int k0 = 0; k0 < K; k0 += 64) {
        {   // A: 256 chunks, 1 per thread
            const int row = tid >> 3, k8 = tid & 7;
            gload16(A + (size_t)(m0 + row) * K + k0 + k8 * 8, As + tid * 16);
        }
        #pragma unroll
        for (int j = 0; j < 8; ++j) {            // B: 2048 chunks
            const int i = j * 256 + tid;
            const int row = i >> 3, k8 = i & 7;
            gload16(W + (size_t)row * K + k0 + k8 * 8, Bs + i * 16);
        }
        __syncthreads();
        #pragma unroll
        for (int ks = 0; ks < 2; ++ks) {
            bf16x8 af[2], bfr[4];
            #pragma unroll
            for (int m = 0; m < 2; ++m) {
                const int off = (m * 16 + (lane & 15)) * 128
                              + ks * 64 + (lane >> 4) * 16;
                af[m] = *(const bf16x8*)(As + off);
            }
            #pragma unroll
            for (int n = 0; n < 4; ++n) {
                const int off = (wid * 64 + n * 16 + (lane & 15)) * 128
                              + ks * 64 + (lane >> 4) * 16;
                bfr[n] = *(const bf16x8*)(Bs + off);
            }
            #pragma unroll
            for (int m = 0; m < 2; ++m)
                #pragma unroll
                for (int n = 0; n < 4; ++n)
                    acc[m][n] = __builtin_amdgcn_mfma_f32_16x16x32_bf16(
                        af[m], bfr[n], acc[m][n], 0, 0, 0);
        }
        __syncthreads();
    }

    // bias + residual -> Xs (fp32)
    #pragma unroll
    for (int n = 0; n < 4; ++n) {
        const int c = wid * 64 + n * 16 + (lane & 15);
        const float bv = bias[c];
        #pragma unroll
        for (int m = 0; m < 2; ++m) {
            const int rb = m * 16 + ((lane >> 4) << 2);
            #pragma unroll
            for (int j = 0; j < 4; ++j) {
                const int r = rb + j;
                float v = acc[m][n][j] + bv;
                if (RES_F32)
                    v += ((const float*)resv)[(size_t)(m0 + r) * 256 + c];
                else
                    v += bf2f(((const unsigned short*)resv)[(size_t)(m0 + r) * 256 + c]);
                Xs[r * 264 + c] = v;
            }
        }
    }
    __syncthreads();

    // LayerNorm: one wave per row, 8 rows per wave
    #pragma unroll
    for (int it = 0; it < 8; ++it) {
        const int row = wid * 8 + it;
        float4 v = *(const float4*)(Xs + row * 264 + lane * 4);
        float s  = v.x + v.y + v.z + v.w;
        float sq = v.x * v.x + v.y * v.y + v.z * v.z + v.w * v.w;
        #pragma unroll
        for (int m = 1; m <= 32; m <<= 1) {
            s  += __shfl_xor(s, m);
            sq += __shfl_xor(sq, m);
        }
        const float mean = s * (1.f / 256.f);
        const float var  = sq * (1.f / 256.f) - mean * mean;
        const float rstd = rsqrtf(var + LN_EPS);
        float4 gm = *(const float4*)(gamma + lane * 4);
        float4 bt = *(const float4*)(beta + lane * 4);
        float4 o;
        o.x = (v.x - mean) * rstd * gm.x + bt.x;
        o.y = (v.y - mean) * rstd * gm.y + bt.y;
        o.z = (v.z - mean) * rstd * gm.z + bt.z;
        o.w = (v.w - mean) * rstd * gm.w + bt.w;
        if (OUT_F32) {
            *(float4*)((float*)outv + (size_t)(m0 + row) * 256 + lane * 4) = o;
        } else {
            u16x4 p;
            p[0] = f2bf(o.x); p[1] = f2bf(o.y); p[2] = f2bf(o.z); p[3] = f2bf(o.w);
            *(u16x4*)((unsigned short*)outv + (size_t)(m0 + row) * 256 + lane * 4) = p;
        }
    }
}

// ---------------------------------------------------------------------------
// Windowed attention, no LDS: one thread per (t, h). Static 9-tap unroll with
// -inf masking of out-of-range taps (clamped addresses stay in bounds).
// qkv bf16 [B,T,768] (q|k|v), o bf16 [B,T,256].
// ---------------------------------------------------------------------------
__global__ __launch_bounds__(256) void attn_win9(
    const unsigned short* __restrict__ qkv, unsigned short* __restrict__ o)
{
    const int t = blockIdx.x * 256 + threadIdx.x;
    const int h = blockIdx.y, b = blockIdx.z;
    const unsigned short* base = qkv + (size_t)b * T_LEN * 768;

    float q[32];
    {
        const unsigned short* qp = base + (size_t)t * 768 + h * 32;
        #pragma unroll
        for (int jj = 0; jj < 4; ++jj) {
            u16x8 u = *(const u16x8*)(qp + jj * 8);
            #pragma unroll
            for (int e = 0; e < 8; ++e) q[jj * 8 + e] = bf2f(u[e]);
        }
    }

    const unsigned short* kbase = base + 256 + h * 32;
    const unsigned short* vbase = base + 512 + h * 32;

    float sc[9], mx = -1e30f;
    #pragma unroll
    for (int j = 0; j < 9; ++j) {
        const int kr0 = t - 4 + j;
        const int krm = min(max(kr0, 0), T_LEN - 1);
        const unsigned short* kr = kbase + (size_t)krm * 768;
        float d = 0.f;
        #pragma unroll
        for (int jj = 0; jj < 4; ++jj) {
            u16x8 u = *(const u16x8*)(kr + jj * 8);
            #pragma unroll
            for (int e = 0; e < 8; ++e) d += q[jj * 8 + e] * bf2f(u[e]);
        }
        sc[j] = (kr0 == krm) ? d * 0.17677669529663687f : -1e30f;
        mx = fmaxf(mx, sc[j]);
    }
    float sum = 0.f;
    #pragma unroll
    for (int j = 0; j < 9; ++j) { sc[j] = expf(sc[j] - mx); sum += sc[j]; }
    const float inv = 1.f / sum;

    float ov[32] = {};
    #pragma unroll
    for (int j = 0; j < 9; ++j) {
        const float p = sc[j] * inv;
        const int krm = min(max(t - 4 + j, 0), T_LEN - 1);
        const unsigned short* vr = vbase + (size_t)krm * 768;
        #pragma unroll
        for (int jj = 0; jj < 4; ++jj) {
            u16x8 u = *(const u16x8*)(vr + jj * 8);
            #pragma unroll
            for (int e = 0; e < 8; ++e) ov[jj * 8 + e] += p * bf2f(u[e]);
        }
    }

    unsigned short* op = o + ((size_t)b * T_LEN + t) * 256 + h * 32;
    #pragma unroll
    for (int jj = 0; jj < 4; ++jj) {
        u16x8 p8;
        #pragma unroll
        for (int e = 0; e < 8; ++e) p8[e] = f2bf(ov[jj * 8 + e]);
        *(u16x8*)(op + jj * 8) = p8;
    }
}

// ---------------------------------------------------------------------------
extern "C" void kernel_launch(void* const* d_in, const int* in_sizes, int n_in,
                              void* d_out, int out_size, void* d_ws, size_t ws_size,
                              hipStream_t stream) {
    const float* features = (const float*)d_in[0];
    const float* w_qkv    = (const float*)d_in[1];
    const float* b_qkv    = (const float*)d_in[2];
    const float* w_out    = (const float*)d_in[3];
    const float* b_out    = (const float*)d_in[4];
    const float* w1       = (const float*)d_in[5];
    const float* b1       = (const float*)d_in[6];
    const float* w2       = (const float*)d_in[7];
    const float* b2       = (const float*)d_in[8];
    const float* g1       = (const float*)d_in[9];
    const float* be1      = (const float*)d_in[10];
    const float* g2       = (const float*)d_in[11];
    const float* be2      = (const float*)d_in[12];
    // d_in[13] (mask) structurally determined by WIN=9 -> not read.

    unsigned short* wsu = (unsigned short*)d_ws;
    unsigned short* featbf  = wsu;              // 2,097,152
    unsigned short* wqkvbf  = wsu + 2097152;    //   196,608
    unsigned short* woutbf  = wsu + 2293760;    //    65,536
    unsigned short* w1bf    = wsu + 2359296;    //   131,072
    unsigned short* w2bf    = wsu + 2490368;    //   131,072
    unsigned short* qkvbf   = wsu + 2621440;    // [8192][768]
    unsigned short* obf     = wsu + 8912896;    // [8192][256]
    unsigned short* xbf     = wsu + 11010048;   // [8192][256]
    unsigned short* hidbf   = wsu + 13107200;   // [8192][512]

    // 0) convert weights + features to bf16 (once per launch)
    to_bf16_multi<<<1280, 256, 0, stream>>>(
        features, w_qkv, w_out, w1, w2, wsu);
    // 1) QKV projection -> qkvbf [8192,768]
    gemm_bf16_128<256, false><<<dim3(64, 6), 256, 0, stream>>>(
        featbf, wqkvbf, b_qkv, qkvbf, 768);
    // 2) windowed attention -> obf
    attn_win9<<<dim3(T_LEN / 256, H_NUM, B_NUM), 256, 0, stream>>>(qkvbf, obf);
    // 3) out-proj + bias + residual(features f32) + LN1 -> xbf
    gemm_ln32<256, true, false><<<M_ROWS / 32, 256, 0, stream>>>(
        obf, woutbf, b_out, features, g1, be1, xbf);
    // 4) FFN up + relu -> hidbf
    gemm_bf16_128<256, true><<<dim3(64, 4), 256, 0, stream>>>(
        xbf, w1bf, b1, hidbf, 512);
    // 5) FFN down + bias + residual(xbf) + LN2 -> d_out (fp32)
    gemm_ln32<512, false, true><<<M_ROWS / 32, 256, 0, stream>>>(
        hidbf, w2bf, b2, xbf, g2, be2, (float*)d_out);
}

// Round 4
// 53.739 us; speedup vs baseline: 9.7368x; 1.2181x over previous
//
#include <hip/hip_runtime.h>
#include <math.h>

#define T_LEN 2048
#define D_DIM 256
#define H_NUM 8
#define B_NUM 4
#define M_ROWS 8192
#define LN_EPS 1e-5f

using u16x8  = __attribute__((ext_vector_type(8))) unsigned short;
using u16x4  = __attribute__((ext_vector_type(4))) unsigned short;
using bf16x8 = __attribute__((ext_vector_type(8))) short;
using f32x4  = __attribute__((ext_vector_type(4))) float;

__device__ __forceinline__ unsigned short f2bf(float f) {
    unsigned int u = __float_as_uint(f);
    u += 0x7FFFu + ((u >> 16) & 1u);
    return (unsigned short)(u >> 16);
}
__device__ __forceinline__ float bf2f(unsigned short u) {
    return __uint_as_float(((unsigned int)u) << 16);
}
__device__ __forceinline__ void gload16(const void* g, void* l) {
    __builtin_amdgcn_global_load_lds(
        (const __attribute__((address_space(1))) unsigned int*)g,
        (__attribute__((address_space(3))) unsigned int*)l, 16, 0, 0);
}

// ---------------------------------------------------------------------------
// fp32 -> bf16 of {features, w_qkv, w_out, w1, w2}.
// ---------------------------------------------------------------------------
__global__ __launch_bounds__(256) void to_bf16_multi(
    const float* __restrict__ s0, const float* __restrict__ s1,
    const float* __restrict__ s2, const float* __restrict__ s3,
    const float* __restrict__ s4, unsigned short* __restrict__ dst)
{
    const long i8 = ((long)blockIdx.x * 256 + threadIdx.x) * 8;
    const float* src; long off;
    if (i8 < 2097152)      { src = s0; off = 0; }
    else if (i8 < 2293760) { src = s1; off = 2097152; }
    else if (i8 < 2359296) { src = s2; off = 2293760; }
    else if (i8 < 2490368) { src = s3; off = 2359296; }
    else                   { src = s4; off = 2490368; }
    const float4 a = *(const float4*)(src + (i8 - off));
    const float4 b = *(const float4*)(src + (i8 - off) + 4);
    u16x8 p;
    p[0] = f2bf(a.x); p[1] = f2bf(a.y); p[2] = f2bf(a.z); p[3] = f2bf(a.w);
    p[4] = f2bf(b.x); p[5] = f2bf(b.y); p[6] = f2bf(b.z); p[7] = f2bf(b.w);
    *(u16x8*)(dst + i8) = p;
}

// ---------------------------------------------------------------------------
// QKV GEMM: C[8192,768] = A[8192,256] @ W[768,256]^T + bias. bf16.
// 128x192 tile, 512 threads (8 waves, 2x4), grid 64x4 = 256 (tail-free).
// Staging uses pre-swizzled global source + XOR reads (T2 both-sides).
// ---------------------------------------------------------------------------
__global__ __launch_bounds__(512) void qkv_gemm(
    const unsigned short* __restrict__ A, const unsigned short* __restrict__ W,
    const float* __restrict__ bias, unsigned short* __restrict__ C)
{
    __shared__ char sm[16384 + 24576];   // As [128][64], Bs [192][64]
    char* As = sm;
    char* Bs = sm + 16384;

    const int tid = threadIdx.x, lane = tid & 63, wid = tid >> 6;
    const int wr = wid >> 2, wcl = wid & 3;
    const int m0 = blockIdx.x * 128, n0 = blockIdx.y * 192;

    f32x4 acc[4][3];
    #pragma unroll
    for (int m = 0; m < 4; ++m)
        #pragma unroll
        for (int n = 0; n < 3; ++n) acc[m][n] = (f32x4)(0.f);

    for (int k0 = 0; k0 < 256; k0 += 64) {
        #pragma unroll
        for (int j = 0; j < 5; ++j) {
            const int i = j * 512 + tid;               // 0..2559
            if (i < 1024) {
                const int row = i >> 3, k8 = (i & 7) ^ (row & 7);
                gload16(A + (size_t)(m0 + row) * 256 + k0 + k8 * 8, As + i * 16);
            } else {
                const int ii = i - 1024;
                const int row = ii >> 3, k8 = (ii & 7) ^ (row & 7);
                gload16(W + (size_t)(n0 + row) * 256 + k0 + k8 * 8, Bs + ii * 16);
            }
        }
        __syncthreads();
        #pragma unroll
        for (int ks = 0; ks < 2; ++ks) {
            bf16x8 af[4], bfr[3];
            #pragma unroll
            for (int m = 0; m < 4; ++m) {
                const int row = wr * 64 + m * 16 + (lane & 15);
                const int off = (row * 128 + ks * 64 + (lane >> 4) * 16) ^ ((row & 7) << 4);
                af[m] = *(const bf16x8*)(As + off);
            }
            #pragma unroll
            for (int n = 0; n < 3; ++n) {
                const int row = wcl * 48 + n * 16 + (lane & 15);
                const int off = (row * 128 + ks * 64 + (lane >> 4) * 16) ^ ((row & 7) << 4);
                bfr[n] = *(const bf16x8*)(Bs + off);
            }
            #pragma unroll
            for (int m = 0; m < 4; ++m)
                #pragma unroll
                for (int n = 0; n < 3; ++n)
                    acc[m][n] = __builtin_amdgcn_mfma_f32_16x16x32_bf16(
                        af[m], bfr[n], acc[m][n], 0, 0, 0);
        }
        __syncthreads();
    }

    #pragma unroll
    for (int n = 0; n < 3; ++n) {
        const int c = n0 + wcl * 48 + n * 16 + (lane & 15);
        const float bv = bias[c];
        #pragma unroll
        for (int m = 0; m < 4; ++m) {
            const int rbase = m0 + wr * 64 + m * 16 + ((lane >> 4) << 2);
            #pragma unroll
            for (int j = 0; j < 4; ++j)
                C[(size_t)(rbase + j) * 768 + c] = f2bf(acc[m][n][j] + bv);
        }
    }
}

// ---------------------------------------------------------------------------
// FFN1: C[8192,512] = relu(A[8192,256] @ W[512,256]^T + bias). bf16.
// 128x128 tile, 4 waves (2x2), grid 64x4 = 256. Swizzled staging.
// ---------------------------------------------------------------------------
__global__ __launch_bounds__(256) void ffn1_gemm(
    const unsigned short* __restrict__ A, const unsigned short* __restrict__ W,
    const float* __restrict__ bias, unsigned short* __restrict__ C)
{
    __shared__ char sm[32768];
    char* As = sm;
    char* Bs = sm + 16384;

    const int tid = threadIdx.x, lane = tid & 63, wid = tid >> 6;
    const int wr = wid >> 1, wc = wid & 1;
    const int m0 = blockIdx.x * 128, n0 = blockIdx.y * 128;

    f32x4 acc[4][4];
    #pragma unroll
    for (int m = 0; m < 4; ++m)
        #pragma unroll
        for (int n = 0; n < 4; ++n) acc[m][n] = (f32x4)(0.f);

    for (int k0 = 0; k0 < 256; k0 += 64) {
        #pragma unroll
        for (int j = 0; j < 4; ++j) {
            const int i = j * 256 + tid;
            const int row = i >> 3, k8 = (i & 7) ^ (row & 7);
            gload16(A + (size_t)(m0 + row) * 256 + k0 + k8 * 8, As + i * 16);
            gload16(W + (size_t)(n0 + row) * 256 + k0 + k8 * 8, Bs + i * 16);
        }
        __syncthreads();
        #pragma unroll
        for (int ks = 0; ks < 2; ++ks) {
            bf16x8 af[4], bfr[4];
            #pragma unroll
            for (int m = 0; m < 4; ++m) {
                const int row = wr * 64 + m * 16 + (lane & 15);
                const int off = (row * 128 + ks * 64 + (lane >> 4) * 16) ^ ((row & 7) << 4);
                af[m] = *(const bf16x8*)(As + off);
            }
            #pragma unroll
            for (int n = 0; n < 4; ++n) {
                const int row = wc * 64 + n * 16 + (lane & 15);
                const int off = (row * 128 + ks * 64 + (lane >> 4) * 16) ^ ((row & 7) << 4);
                bfr[n] = *(const bf16x8*)(Bs + off);
            }
            #pragma unroll
            for (int m = 0; m < 4; ++m)
                #pragma unroll
                for (int n = 0; n < 4; ++n)
                    acc[m][n] = __builtin_amdgcn_mfma_f32_16x16x32_bf16(
                        af[m], bfr[n], acc[m][n], 0, 0, 0);
        }
        __syncthreads();
    }

    #pragma unroll
    for (int n = 0; n < 4; ++n) {
        const int c = n0 + wc * 64 + n * 16 + (lane & 15);
        const float bv = bias[c];
        #pragma unroll
        for (int m = 0; m < 4; ++m) {
            const int rbase = m0 + wr * 64 + m * 16 + ((lane >> 4) << 2);
            #pragma unroll
            for (int j = 0; j < 4; ++j)
                C[(size_t)(rbase + j) * 512 + c] = f2bf(fmaxf(acc[m][n][j] + bv, 0.f));
        }
    }
}

// ---------------------------------------------------------------------------
// Shared epilogue: bias + residual + LayerNorm, fully in registers.
// acc[2][4] covers 32 rows x 256 cols (4 waves x 64 cols).
// ---------------------------------------------------------------------------
template<bool RES_F32, bool OUT_F32>
__device__ __forceinline__ void ln_epilogue(
    f32x4 (&acc)[2][4], float (*part)[32][2],
    const float* __restrict__ bias, const void* __restrict__ resv,
    const float* __restrict__ gamma, const float* __restrict__ beta,
    void* __restrict__ outv, int m0, int lane, int wid)
{
    float v[2][4][4];
    float s[2][4], sq[2][4];
    #pragma unroll
    for (int m = 0; m < 2; ++m)
        #pragma unroll
        for (int j = 0; j < 4; ++j) { s[m][j] = 0.f; sq[m][j] = 0.f; }

    #pragma unroll
    for (int n = 0; n < 4; ++n) {
        const int c = wid * 64 + n * 16 + (lane & 15);
        const float bv = bias[c];
        #pragma unroll
        for (int m = 0; m < 2; ++m) {
            const int rb = m * 16 + ((lane >> 4) << 2);
            #pragma unroll
            for (int j = 0; j < 4; ++j) {
                float x = acc[m][n][j] + bv;
                if (RES_F32)
                    x += ((const float*)resv)[(size_t)(m0 + rb + j) * 256 + c];
                else
                    x += bf2f(((const unsigned short*)resv)[(size_t)(m0 + rb + j) * 256 + c]);
                v[m][n][j] = x;
                s[m][j] += x;
                sq[m][j] += x * x;
            }
        }
    }
    #pragma unroll
    for (int m = 0; m < 2; ++m)
        #pragma unroll
        for (int j = 0; j < 4; ++j) {
            #pragma unroll
            for (int msk = 1; msk <= 8; msk <<= 1) {
                s[m][j]  += __shfl_xor(s[m][j], msk);
                sq[m][j] += __shfl_xor(sq[m][j], msk);
            }
            if ((lane & 15) == 0) {
                const int r32 = m * 16 + ((lane >> 4) << 2) + j;
                part[wid][r32][0] = s[m][j];
                part[wid][r32][1] = sq[m][j];
            }
        }
    __syncthreads();

    #pragma unroll
    for (int m = 0; m < 2; ++m) {
        const int rb = m * 16 + ((lane >> 4) << 2);
        #pragma unroll
        for (int j = 0; j < 4; ++j) {
            const int r32 = rb + j;
            float S = 0.f, SQ = 0.f;
            #pragma unroll
            for (int w = 0; w < 4; ++w) { S += part[w][r32][0]; SQ += part[w][r32][1]; }
            const float mean = S * (1.f / 256.f);
            const float var  = SQ * (1.f / 256.f) - mean * mean;
            const float rstd = rsqrtf(var + LN_EPS);
            #pragma unroll
            for (int n = 0; n < 4; ++n) {
                const int c = wid * 64 + n * 16 + (lane & 15);
                const float o = (v[m][n][j] - mean) * rstd * gamma[c] + beta[c];
                if (OUT_F32)
                    ((float*)outv)[(size_t)(m0 + r32) * 256 + c] = o;
                else
                    ((unsigned short*)outv)[(size_t)(m0 + r32) * 256 + c] = f2bf(o);
            }
        }
    }
}

// ---------------------------------------------------------------------------
// Fused: windowed attention (32 rows x 8 heads) -> out-proj -> +res -> LN1.
// Block = 32 rows (one batch each), 256 threads. A-tile built in LDS by the
// attention phase (XOR-swizzled); W streamed via gload16.
// ---------------------------------------------------------------------------
__global__ __launch_bounds__(256) void attn_proj_ln(
    const unsigned short* __restrict__ qkv, const unsigned short* __restrict__ Wo,
    const float* __restrict__ bias, const float* __restrict__ resf,
    const float* __restrict__ gamma, const float* __restrict__ beta,
    unsigned short* __restrict__ out)
{
    __shared__ char sm[16384 + 32768];   // As [32][256] bf16, Bs [256][64]
    __shared__ float part[4][32][2];
    char* As = sm;
    char* Bs = sm + 16384;

    const int tid = threadIdx.x, lane = tid & 63, wid = tid >> 6;
    const int m0 = blockIdx.x * 32;
    const int b = m0 >> 11, t0 = m0 & 2047;

    // ---- attention: one thread per (t_local, head) ----
    {
        const int h = tid & 7, tl = tid >> 3;
        const int t = t0 + tl;
        const unsigned short* base = qkv + (size_t)b * T_LEN * 768;

        float q[32];
        const unsigned short* qp = base + (size_t)t * 768 + h * 32;
        #pragma unroll
        for (int jj = 0; jj < 4; ++jj) {
            u16x8 u = *(const u16x8*)(qp + jj * 8);
            #pragma unroll
            for (int e = 0; e < 8; ++e) q[jj * 8 + e] = bf2f(u[e]);
        }
        const unsigned short* kbase = base + 256 + h * 32;
        const unsigned short* vbase = base + 512 + h * 32;

        float sc[9], mx = -1e30f;
        #pragma unroll
        for (int j = 0; j < 9; ++j) {
            const int kr0 = t - 4 + j;
            const int krm = min(max(kr0, 0), T_LEN - 1);
            const unsigned short* kr = kbase + (size_t)krm * 768;
            float d = 0.f;
            #pragma unroll
            for (int jj = 0; jj < 4; ++jj) {
                u16x8 u = *(const u16x8*)(kr + jj * 8);
                #pragma unroll
                for (int e = 0; e < 8; ++e) d += q[jj * 8 + e] * bf2f(u[e]);
            }
            sc[j] = (kr0 == krm) ? d * 0.17677669529663687f : -1e30f;
            mx = fmaxf(mx, sc[j]);
        }
        float sum = 0.f;
        #pragma unroll
        for (int j = 0; j < 9; ++j) { sc[j] = expf(sc[j] - mx); sum += sc[j]; }
        const float inv = 1.f / sum;

        float ov[32] = {};
        #pragma unroll
        for (int j = 0; j < 9; ++j) {
            const float p = sc[j] * inv;
            const int krm = min(max(t - 4 + j, 0), T_LEN - 1);
            const unsigned short* vr = vbase + (size_t)krm * 768;
            #pragma unroll
            for (int jj = 0; jj < 4; ++jj) {
                u16x8 u = *(const u16x8*)(vr + jj * 8);
                #pragma unroll
                for (int e = 0; e < 8; ++e) ov[jj * 8 + e] += p * bf2f(u[e]);
            }
        }
        // write to As [32][256] with XOR swizzle
        #pragma unroll
        for (int jj = 0; jj < 4; ++jj) {
            u16x8 p8;
            #pragma unroll
            for (int e = 0; e < 8; ++e) p8[e] = f2bf(ov[jj * 8 + e]);
            const int off = (tl * 512 + h * 64 + jj * 16) ^ ((tl & 7) << 4);
            *(u16x8*)(As + off) = p8;
        }
    }
    __syncthreads();

    // ---- GEMM: 32x256 @ Wo[256,256]^T ----
    f32x4 acc[2][4];
    #pragma unroll
    for (int m = 0; m < 2; ++m)
        #pragma unroll
        for (int n = 0; n < 4; ++n) acc[m][n] = (f32x4)(0.f);

    for (int k0 = 0; k0 < 256; k0 += 64) {
        #pragma unroll
        for (int j = 0; j < 8; ++j) {
            const int i = j * 256 + tid;
            const int row = i >> 3, k8 = (i & 7) ^ (row & 7);
            gload16(Wo + (size_t)row * 256 + k0 + k8 * 8, Bs + i * 16);
        }
        __syncthreads();
        #pragma unroll
        for (int ks = 0; ks < 2; ++ks) {
            bf16x8 af[2], bfr[4];
            #pragma unroll
            for (int m = 0; m < 2; ++m) {
                const int row = m * 16 + (lane & 15);
                const int off = (row * 512 + (k0 + ks * 32 + (lane >> 4) * 8) * 2) ^ ((row & 7) << 4);
                af[m] = *(const bf16x8*)(As + off);
            }
            #pragma unroll
            for (int n = 0; n < 4; ++n) {
                const int row = wid * 64 + n * 16 + (lane & 15);
                const int off = (row * 128 + ks * 64 + (lane >> 4) * 16) ^ ((row & 7) << 4);
                bfr[n] = *(const bf16x8*)(Bs + off);
            }
            #pragma unroll
            for (int m = 0; m < 2; ++m)
                #pragma unroll
                for (int n = 0; n < 4; ++n)
                    acc[m][n] = __builtin_amdgcn_mfma_f32_16x16x32_bf16(
                        af[m], bfr[n], acc[m][n], 0, 0, 0);
        }
        __syncthreads();
    }

    ln_epilogue<true, false>(acc, part, bias, resf, gamma, beta, out, m0, lane, wid);
}

// ---------------------------------------------------------------------------
// FFN2 + residual + LN2: out[M,256] = LN(A[M,512] @ W[256,512]^T + b + res).
// 32-row blocks, 4 waves, in-register LN. Swizzled staging.
// ---------------------------------------------------------------------------
__global__ __launch_bounds__(256) void ffn2_ln(
    const unsigned short* __restrict__ A, const unsigned short* __restrict__ W,
    const float* __restrict__ bias, const unsigned short* __restrict__ resb,
    const float* __restrict__ gamma, const float* __restrict__ beta,
    float* __restrict__ out)
{
    __shared__ char sm[4096 + 32768];    // As [32][64], Bs [256][64]
    __shared__ float part[4][32][2];
    char* As = sm;
    char* Bs = sm + 4096;

    const int tid = threadIdx.x, lane = tid & 63, wid = tid >> 6;
    const int m0 = blockIdx.x * 32;

    f32x4 acc[2][4];
    #pragma unroll
    for (int m = 0; m < 2; ++m)
        #pragma unroll
        for (int n = 0; n < 4; ++n) acc[m][n] = (f32x4)(0.f);

    for (int k0 = 0; k0 < 512; k0 += 64) {
        {
            const int row = tid >> 3, k8 = (tid & 7) ^ (row & 7);
            gload16(A + (size_t)(m0 + row) * 512 + k0 + k8 * 8, As + tid * 16);
        }
        #pragma unroll
        for (int j = 0; j < 8; ++j) {
            const int i = j * 256 + tid;
            const int row = i >> 3, k8 = (i & 7) ^ (row & 7);
            gload16(W + (size_t)row * 512 + k0 + k8 * 8, Bs + i * 16);
        }
        __syncthreads();
        #pragma unroll
        for (int ks = 0; ks < 2; ++ks) {
            bf16x8 af[2], bfr[4];
            #pragma unroll
            for (int m = 0; m < 2; ++m) {
                const int row = m * 16 + (lane & 15);
                const int off = (row * 128 + ks * 64 + (lane >> 4) * 16) ^ ((row & 7) << 4);
                af[m] = *(const bf16x8*)(As + off);
            }
            #pragma unroll
            for (int n = 0; n < 4; ++n) {
                const int row = wid * 64 + n * 16 + (lane & 15);
                const int off = (row * 128 + ks * 64 + (lane >> 4) * 16) ^ ((row & 7) << 4);
                bfr[n] = *(const bf16x8*)(Bs + off);
            }
            #pragma unroll
            for (int m = 0; m < 2; ++m)
                #pragma unroll
                for (int n = 0; n < 4; ++n)
                    acc[m][n] = __builtin_amdgcn_mfma_f32_16x16x32_bf16(
                        af[m], bfr[n], acc[m][n], 0, 0, 0);
        }
        __syncthreads();
    }

    ln_epilogue<false, true>(acc, part, bias, resb, gamma, beta, out, m0, lane, wid);
}

// ---------------------------------------------------------------------------
extern "C" void kernel_launch(void* const* d_in, const int* in_sizes, int n_in,
                              void* d_out, int out_size, void* d_ws, size_t ws_size,
                              hipStream_t stream) {
    const float* features = (const float*)d_in[0];
    const float* w_qkv    = (const float*)d_in[1];
    const float* b_qkv    = (const float*)d_in[2];
    const float* w_out    = (const float*)d_in[3];
    const float* b_out    = (const float*)d_in[4];
    const float* w1       = (const float*)d_in[5];
    const float* b1       = (const float*)d_in[6];
    const float* w2       = (const float*)d_in[7];
    const float* b2       = (const float*)d_in[8];
    const float* g1       = (const float*)d_in[9];
    const float* be1      = (const float*)d_in[10];
    const float* g2       = (const float*)d_in[11];
    const float* be2      = (const float*)d_in[12];
    // d_in[13] (mask) structurally determined by WIN=9 -> not read.

    unsigned short* wsu = (unsigned short*)d_ws;
    unsigned short* featbf = wsu;               // 2,097,152
    unsigned short* wqkvbf = wsu + 2097152;     //   196,608
    unsigned short* woutbf = wsu + 2293760;     //    65,536
    unsigned short* w1bf   = wsu + 2359296;     //   131,072
    unsigned short* w2bf   = wsu + 2490368;     //   131,072
    unsigned short* qkvbf  = wsu + 2621440;     // [8192][768]
    unsigned short* xbf    = wsu + 8912896;     // [8192][256]
    unsigned short* hidbf  = wsu + 11010048;    // [8192][512]

    // 0) convert weights + features to bf16
    to_bf16_multi<<<1280, 256, 0, stream>>>(features, w_qkv, w_out, w1, w2, wsu);
    // 1) QKV projection
    qkv_gemm<<<dim3(64, 4), 512, 0, stream>>>(featbf, wqkvbf, b_qkv, qkvbf);
    // 2) attention + out-proj + residual(features) + LN1 -> xbf
    attn_proj_ln<<<M_ROWS / 32, 256, 0, stream>>>(
        qkvbf, woutbf, b_out, features, g1, be1, xbf);
    // 3) FFN up + relu -> hidbf
    ffn1_gemm<<<dim3(64, 4), 256, 0, stream>>>(xbf, w1bf, b1, hidbf);
    // 4) FFN down + residual(xbf) + LN2 -> d_out (fp32)
    ffn2_ln<<<M_ROWS / 32, 256, 0, stream>>>(
        hidbf, w2bf, b2, xbf, g2, be2, (float*)d_out);
}